// Round 1
// baseline (380.973 us; speedup 1.0000x reference)
//
#include <hip/hip_runtime.h>
#include <math.h>

// CRF mean-field with dense Gaussian filters, computed matrix-free.
// K[n,m] = e_n * e_m * exp2(fhat_n . fhat_m), fhat = f * sqrt(log2 e).
// N = 32*16*16 = 8192, C = 4, ALPHA=BETA=GAMMA=5, W1=W2=1, 5 iterations.

constexpr int   NT   = 8192;
constexpr float SQL2E = 1.2011224087864498f;        // sqrt(log2(e))
constexpr float INVA  = 0.2f * SQL2E;               // (1/5) * sqrt(log2 e)
constexpr float W1C = 1.0f, W2C = 1.0f;

// ws layout (float units of NT):
//  0-4 : fs0,fs1,fs2,ff0,ff1   (features pre-scaled by sqrt(log2 e))
//  5-8 : u1[c]   9-12 : u2[c]
//  13 : e1   14 : e2   15 : scale1   16 : scale2
//  17.. : partial buffers (rs aliases y1p; rs used before y1p)

// ---------------------------------------------------------------- setup
__global__ void k_setup(const float* __restrict__ feat, float* __restrict__ W) {
    int n = blockIdx.x * 256 + threadIdx.x;
    if (n >= NT) return;
    int x = n >> 8;          // n / (16*16)
    int y = (n >> 4) & 15;
    int z = n & 15;
    float fs0 = x * INVA, fs1 = y * INVA, fs2 = z * INVA;
    float g0 = feat[n] * INVA, g1 = feat[NT + n] * INVA;
    float s2 = fs0*fs0 + fs1*fs1 + fs2*fs2;
    // e = exp(-0.5*|f|^2) = exp2(-0.5*|fhat|^2)  (fhat scaled by sqrt(log2e))
    float e2 = exp2f(-0.5f * s2);
    float e1 = exp2f(-0.5f * (s2 + g0*g0 + g1*g1));
    W[0*NT+n]=fs0; W[1*NT+n]=fs1; W[2*NT+n]=fs2; W[3*NT+n]=g0; W[4*NT+n]=g1;
    W[13*NT+n]=e1; W[14*NT+n]=e2;
}

// ---------------------------------------------------------------- norm pass
// rowsum partial: rs1p[k][n] = sum_{m in chunk k} e1[m]*exp2(dot1), same rs2p.
template<int KC>
__global__ __launch_bounds__(256) void k_norm(const float* __restrict__ W,
                                              float* __restrict__ rs1p,
                                              float* __restrict__ rs2p) {
    constexpr int MC = NT / KC;
    __shared__ float sm[MC][8];
    const int k = blockIdx.x;
    const int m0 = k * MC;
    for (int s = threadIdx.x; s < MC * 7; s += 256) {
        int m = s / 7, j = s % 7;
        int src = (j < 5) ? j : (j == 5 ? 13 : 14);
        sm[m][j] = W[src * NT + m0 + m];
    }
    __syncthreads();
    const int nb = blockIdx.y * 1024 + threadIdx.x;   // 4 n's per thread
    float a0[4], a1[4], a2[4], b0[4], b1[4], r1[4], r2[4];
#pragma unroll
    for (int i = 0; i < 4; i++) {
        int n = nb + i * 256;
        a0[i] = W[n]; a1[i] = W[NT+n]; a2[i] = W[2*NT+n];
        b0[i] = W[3*NT+n]; b1[i] = W[4*NT+n];
        r1[i] = 0.f; r2[i] = 0.f;
    }
    for (int m = 0; m < MC; m++) {
        float c0 = sm[m][0], c1 = sm[m][1], c2 = sm[m][2];
        float c3 = sm[m][3], c4 = sm[m][4], me1 = sm[m][5], me2 = sm[m][6];
#pragma unroll
        for (int i = 0; i < 4; i++) {
            float ds = fmaf(a0[i], c0, fmaf(a1[i], c1, a2[i]*c2));   // spatial dot (log2 dom)
            float dt = fmaf(b0[i], c3, fmaf(b1[i], c4, ds));         // + feature dot
            float E2 = exp2f(ds);
            float E1 = exp2f(dt);
            r1[i] = fmaf(E1, me1, r1[i]);
            r2[i] = fmaf(E2, me2, r2[i]);
        }
    }
#pragma unroll
    for (int i = 0; i < 4; i++) {
        int n = nb + i * 256;
        rs1p[k*NT + n] = r1[i];
        rs2p[k*NT + n] = r2[i];
    }
}

// ------------------------------------------------- reduce norms, q0, u arrays
template<int KC>
__global__ __launch_bounds__(256) void k_scale_init(float* __restrict__ W,
        const float* __restrict__ rs1p, const float* __restrict__ rs2p,
        const float* __restrict__ lu) {
    constexpr int KG = KC / 8;
    __shared__ float red[2][8][32];
    int nl = threadIdx.x & 31;
    int kg = threadIdx.x >> 5;
    int n = blockIdx.x * 32 + nl;
    float p1 = 0.f, p2 = 0.f;
    for (int kk = kg*KG; kk < kg*KG + KG; kk++) {
        p1 += rs1p[kk*NT + n];
        p2 += rs2p[kk*NT + n];
    }
    red[0][kg][nl] = p1; red[1][kg][nl] = p2;
    __syncthreads();
    if (threadIdx.x < 32) {
        n = blockIdx.x * 32 + threadIdx.x;
        float r1 = 0.f, r2 = 0.f;
#pragma unroll
        for (int g = 0; g < 8; g++) { r1 += red[0][g][threadIdx.x]; r2 += red[1][g][threadIdx.x]; }
        float e1 = W[13*NT+n], e2 = W[14*NT+n];
        float s1 = rsqrtf(e1 * r1);     // scale = rsqrt(rowsum K)
        float s2 = rsqrtf(e2 * r2);
        W[15*NT+n] = s1; W[16*NT+n] = s2;
        float l0 = lu[n], l1 = lu[NT+n], l2 = lu[2*NT+n], l3 = lu[3*NT+n];
        float mx = fmaxf(fmaxf(l0,l1), fmaxf(l2,l3));
        float q0 = __expf(l0-mx), q1 = __expf(l1-mx), q2 = __expf(l2-mx), q3 = __expf(l3-mx);
        float inv = 1.f / (q0+q1+q2+q3);
        q0*=inv; q1*=inv; q2*=inv; q3*=inv;
        float f1 = s1*e1, f2 = s2*e2;
        W[5*NT+n]=q0*f1; W[6*NT+n]=q1*f1; W[7*NT+n]=q2*f1; W[8*NT+n]=q3*f1;
        W[9*NT+n]=q0*f2; W[10*NT+n]=q1*f2; W[11*NT+n]=q2*f2; W[12*NT+n]=q3*f2;
    }
}

// ---------------------------------------------------------------- pair pass
// y1p[c][k][n] = sum_{m in chunk k} exp2(dot1) * u1[c][m] (and y2p with dot2).
template<int KC>
__global__ __launch_bounds__(256) void k_pair(const float* __restrict__ W,
        float* __restrict__ y1p, float* __restrict__ y2p) {
    constexpr int MC = NT / KC;
    __shared__ float sm[MC][16];
    const int k = blockIdx.x;
    const int m0 = k * MC;
    for (int s = threadIdx.x; s < MC * 13; s += 256) {
        int m = s / 13, j = s % 13;       // j: 0-4 feats, 5-8 u1[c], 9-12 u2[c]
        sm[m][j] = W[j * NT + m0 + m];
    }
    __syncthreads();
    const int nb = blockIdx.y * 1024 + threadIdx.x;
    float a0[4],a1[4],a2[4],b0[4],b1[4];
    float acc1[4][4], acc2[4][4];
#pragma unroll
    for (int i = 0; i < 4; i++) {
        int n = nb + i*256;
        a0[i]=W[n]; a1[i]=W[NT+n]; a2[i]=W[2*NT+n]; b0[i]=W[3*NT+n]; b1[i]=W[4*NT+n];
#pragma unroll
        for (int c = 0; c < 4; c++) { acc1[i][c]=0.f; acc2[i][c]=0.f; }
    }
    for (int m = 0; m < MC; m++) {
        float c0=sm[m][0], c1=sm[m][1], c2=sm[m][2], c3=sm[m][3], c4=sm[m][4];
        float u10=sm[m][5], u11=sm[m][6], u12=sm[m][7], u13=sm[m][8];
        float u20=sm[m][9], u21=sm[m][10], u22=sm[m][11], u23=sm[m][12];
#pragma unroll
        for (int i = 0; i < 4; i++) {
            float ds = fmaf(a0[i],c0, fmaf(a1[i],c1, a2[i]*c2));
            float dt = fmaf(b0[i],c3, fmaf(b1[i],c4, ds));
            float E2 = exp2f(ds);
            float E1 = exp2f(dt);
            acc1[i][0] = fmaf(E1,u10,acc1[i][0]);
            acc1[i][1] = fmaf(E1,u11,acc1[i][1]);
            acc1[i][2] = fmaf(E1,u12,acc1[i][2]);
            acc1[i][3] = fmaf(E1,u13,acc1[i][3]);
            acc2[i][0] = fmaf(E2,u20,acc2[i][0]);
            acc2[i][1] = fmaf(E2,u21,acc2[i][1]);
            acc2[i][2] = fmaf(E2,u22,acc2[i][2]);
            acc2[i][3] = fmaf(E2,u23,acc2[i][3]);
        }
    }
#pragma unroll
    for (int i = 0; i < 4; i++) {
        int n = nb + i*256;
#pragma unroll
        for (int c = 0; c < 4; c++) {
            y1p[(c*KC + k)*NT + n] = acc1[i][c];
            y2p[(c*KC + k)*NT + n] = acc2[i][c];
        }
    }
}

// ---------------------------------------- reduce partials, compat, softmax, u
template<int KC>
__global__ __launch_bounds__(256) void k_update(float* __restrict__ W,
        const float* __restrict__ y1p, const float* __restrict__ y2p,
        const float* __restrict__ lu, const float* __restrict__ compat,
        float* __restrict__ out) {
    constexpr int KG = KC / 8;
    __shared__ float red[8][8][32];
    int nl = threadIdx.x & 31;
    int kg = threadIdx.x >> 5;
    int n = blockIdx.x * 32 + nl;
    float p[8];
#pragma unroll
    for (int v = 0; v < 8; v++) p[v] = 0.f;
    for (int kk = kg*KG; kk < kg*KG + KG; kk++) {
#pragma unroll
        for (int c = 0; c < 4; c++) {
            p[c]   += y1p[(c*KC + kk)*NT + n];
            p[4+c] += y2p[(c*KC + kk)*NT + n];
        }
    }
#pragma unroll
    for (int v = 0; v < 8; v++) red[v][kg][nl] = p[v];
    __syncthreads();
    if (threadIdx.x < 32) {
        n = blockIdx.x * 32 + threadIdx.x;
        float y1[4], y2[4];
#pragma unroll
        for (int c = 0; c < 4; c++) {
            float sa = 0.f, sb = 0.f;
#pragma unroll
            for (int g = 0; g < 8; g++) { sa += red[c][g][threadIdx.x]; sb += red[4+c][g][threadIdx.x]; }
            y1[c] = sa; y2[c] = sb;
        }
        float e1 = W[13*NT+n], e2 = W[14*NT+n];
        float s1 = W[15*NT+n], s2 = W[16*NT+n];
        float f1 = s1*e1, f2 = s2*e2;
        float comb[4];
#pragma unroll
        for (int c = 0; c < 4; c++) comb[c] = W1C*f1*y1[c] + W2C*f2*y2[c];
        float q[4];
#pragma unroll
        for (int o = 0; o < 4; o++) {
            float upd = 0.f;
#pragma unroll
            for (int c = 0; c < 4; c++) upd = fmaf(compat[o*4+c], comb[c], upd);
            q[o] = lu[o*NT+n] - upd;
        }
        float mx = fmaxf(fmaxf(q[0],q[1]), fmaxf(q[2],q[3]));
        float sum = 0.f;
#pragma unroll
        for (int c = 0; c < 4; c++) { q[c] = __expf(q[c]-mx); sum += q[c]; }
        float inv = 1.f / sum;
#pragma unroll
        for (int c = 0; c < 4; c++) {
            q[c] *= inv;
            out[c*NT+n]    = q[c];        // overwritten each iter; last one is final
            W[(5+c)*NT+n]  = q[c]*f1;     // u1 for next iteration
            W[(9+c)*NT+n]  = q[c]*f2;     // u2 for next iteration
        }
    }
}

// ---------------------------------------------------------------- launch
template<int KC>
static void run_all(const float* lu, const float* feat, const float* compat,
                    float* out, float* W, hipStream_t stream) {
    float* rs1p = W + 17*NT;
    float* rs2p = W + (17 + KC)*NT;
    float* y1p  = W + 17*NT;                 // aliases rs (rs consumed first)
    float* y2p  = W + (17 + 4*KC)*NT;
    k_norm<KC><<<dim3(KC, 8), dim3(256), 0, stream>>>(W, rs1p, rs2p);
    k_scale_init<KC><<<dim3(256), dim3(256), 0, stream>>>(W, rs1p, rs2p, lu);
    for (int it = 0; it < 5; it++) {
        k_pair<KC><<<dim3(KC, 8), dim3(256), 0, stream>>>(W, y1p, y2p);
        k_update<KC><<<dim3(256), dim3(256), 0, stream>>>(W, y1p, y2p, lu, compat, out);
    }
}

extern "C" void kernel_launch(void* const* d_in, const int* in_sizes, int n_in,
                              void* d_out, int out_size, void* d_ws, size_t ws_size,
                              hipStream_t stream) {
    const float* lu     = (const float*)d_in[0];   // [4][8192] log_unary
    const float* feat   = (const float*)d_in[1];   // [2][8192] pairwise features
    const float* compat = (const float*)d_in[2];   // [4][4] compatibility
    float* out = (float*)d_out;                    // [4][8192] fp32
    float* W   = (float*)d_ws;

    k_setup<<<dim3(NT/256), dim3(256), 0, stream>>>(feat, W);

    // KC=64: needs (17 + 8*64)*NT floats = 17.3 MB of ws. Fallback KC=16: 4.75 MB.
    if (ws_size >= (size_t)(17 + 8*64) * NT * sizeof(float)) {
        run_all<64>(lu, feat, compat, out, W, stream);
    } else {
        run_all<16>(lu, feat, compat, out, W, stream);
    }
}

// Round 2
// 263.583 us; speedup vs baseline: 1.4454x; 1.4454x over previous
//
#include <hip/hip_runtime.h>
#include <math.h>

// CRF mean-field. Bilateral kernel K1 computed matrix-free:
//   K1[n,m] = e1_n * e1_m * exp2(phi_n . phi_m), phi = (f/5)*sqrt(log2 e).
// Spatial kernel K2 applied as an EXACT separable 1-D Gaussian filter
// (regular grid): O(N*(X+Y+Z)) instead of O(N^2); rowsum2 = Sx*Sy*Sz.
// N = 32*16*16 = 8192, C = 4, ALPHA=BETA=GAMMA=5, W1=W2=1, 5 iterations.

constexpr int   NT    = 8192;
constexpr float SQL2E = 1.2011224087864498f;   // sqrt(log2(e))
constexpr float INVA  = 0.2f * SQL2E;          // (1/5)*sqrt(log2 e)

// W (workspace) rows of NT floats:
//  0-4 : phi (fs0,fs1,fs2,ff0,ff1)
//  5-8 : u1[c] = q*s1*e1        9-12 : u2[c] = q*s2
//  13  : e1    14 : f1 = s1*e1   15 : s2
//  16-19 : y2s[c] (spatial filter output)
//  20.. : y1p partials (4*KC rows); rs1p aliases the first KC rows

static __device__ __forceinline__ float ex2(float x) {
    return __builtin_amdgcn_exp2f(x);
}

// ---------------------------------------------------------------- setup
__global__ void k_setup(const float* __restrict__ feat, float* __restrict__ W) {
    int n = blockIdx.x * 256 + threadIdx.x;
    if (n >= NT) return;
    int x = n >> 8, y = (n >> 4) & 15, z = n & 15;
    float fs0 = x * INVA, fs1 = y * INVA, fs2 = z * INVA;
    float g0 = feat[n] * INVA, g1 = feat[NT + n] * INVA;
    float s2 = fs0*fs0 + fs1*fs1 + fs2*fs2;
    float e1 = ex2(-0.5f * (s2 + g0*g0 + g1*g1));
    W[0*NT+n]=fs0; W[1*NT+n]=fs1; W[2*NT+n]=fs2; W[3*NT+n]=g0; W[4*NT+n]=g1;
    W[13*NT+n]=e1;
}

// ------------------------------------------------- bilateral rowsum partials
template<int KC>
__global__ __launch_bounds__(256) void k_norm(const float* __restrict__ W,
                                              float* __restrict__ rs1p) {
    constexpr int MC = NT / KC;
    __shared__ float sm[MC][8];
    const int k = blockIdx.x, m0 = k * MC;
    for (int s = threadIdx.x; s < MC * 6; s += 256) {
        int m = s / 6, j = s % 6;
        sm[m][j] = W[(j < 5 ? j : 13) * NT + m0 + m];
    }
    __syncthreads();
    const int nb = blockIdx.y * 1024 + threadIdx.x;   // 4 n's per thread
    float a0[4], a1[4], a2[4], b0[4], b1[4], r1[4];
#pragma unroll
    for (int i = 0; i < 4; i++) {
        int n = nb + i * 256;
        a0[i]=W[n]; a1[i]=W[NT+n]; a2[i]=W[2*NT+n]; b0[i]=W[3*NT+n]; b1[i]=W[4*NT+n];
        r1[i] = 0.f;
    }
#pragma unroll 4
    for (int m = 0; m < MC; m++) {
        float c0=sm[m][0], c1=sm[m][1], c2=sm[m][2], c3=sm[m][3], c4=sm[m][4];
        float me1 = sm[m][5];
#pragma unroll
        for (int i = 0; i < 4; i++) {
            float dt = fmaf(a0[i],c0, fmaf(a1[i],c1, fmaf(a2[i],c2, fmaf(b0[i],c3, b1[i]*c4))));
            r1[i] = fmaf(ex2(dt), me1, r1[i]);
        }
    }
#pragma unroll
    for (int i = 0; i < 4; i++) rs1p[k*NT + nb + i*256] = r1[i];
}

// ---------------------------- reduce rowsum, spatial norm (separable), q0, u
template<int KC>
__global__ __launch_bounds__(256) void k_scale_init(float* __restrict__ W,
        const float* __restrict__ rs1p, const float* __restrict__ lu) {
    constexpr int KG = KC / 8;
    __shared__ float red[8][32];
    int nl = threadIdx.x & 31, kg = threadIdx.x >> 5;
    int n = blockIdx.x * 32 + nl;
    float p1 = 0.f;
    for (int kk = kg*KG; kk < kg*KG + KG; kk++) p1 += rs1p[kk*NT + n];
    red[kg][nl] = p1;
    __syncthreads();
    if (threadIdx.x < 32) {
        n = blockIdx.x * 32 + threadIdx.x;
        float r1 = 0.f;
#pragma unroll
        for (int g = 0; g < 8; g++) r1 += red[g][threadIdx.x];
        float e1 = W[13*NT+n];
        float s1 = rsqrtf(e1 * r1);
        // spatial rowsum: exact separable product of 1-D Gaussian sums
        int x = n >> 8, y = (n >> 4) & 15, z = n & 15;
        float Sx = 0.f, Sy = 0.f, Sz = 0.f;
        for (int j = 0; j < 32; j++) { float d = (float)(x - j) * INVA; Sx += ex2(-0.5f*d*d); }
        for (int j = 0; j < 16; j++) { float d = (float)(y - j) * INVA; Sy += ex2(-0.5f*d*d); }
        for (int j = 0; j < 16; j++) { float d = (float)(z - j) * INVA; Sz += ex2(-0.5f*d*d); }
        float s2 = rsqrtf(Sx * Sy * Sz);
        float f1 = s1 * e1;
        W[14*NT+n] = f1; W[15*NT+n] = s2;
        float l0 = lu[n], l1 = lu[NT+n], l2 = lu[2*NT+n], l3 = lu[3*NT+n];
        float mx = fmaxf(fmaxf(l0,l1), fmaxf(l2,l3));
        float q0 = __expf(l0-mx), q1 = __expf(l1-mx), q2 = __expf(l2-mx), q3 = __expf(l3-mx);
        float inv = 1.f / (q0+q1+q2+q3);
        q0*=inv; q1*=inv; q2*=inv; q3*=inv;
        W[5*NT+n]=q0*f1; W[6*NT+n]=q1*f1; W[7*NT+n]=q2*f1; W[8*NT+n]=q3*f1;
        W[9*NT+n]=q0*s2; W[10*NT+n]=q1*s2; W[11*NT+n]=q2*s2; W[12*NT+n]=q3*s2;
    }
}

// ------------------------------------------------- bilateral pair pass (hot)
template<int KC>
__global__ __launch_bounds__(256) void k_pair(const float* __restrict__ W,
                                              float* __restrict__ y1p) {
    constexpr int MC = NT / KC;
    __shared__ float sm[MC][12];
    const int k = blockIdx.x, m0 = k * MC;
    for (int s = threadIdx.x; s < MC * 9; s += 256) {
        int m = s / 9, j = s % 9;          // rows 0-4 feats, 5-8 u1[c]
        sm[m][j] = W[j * NT + m0 + m];
    }
    __syncthreads();
    const int nb = blockIdx.y * 1024 + threadIdx.x;
    float a0[4],a1[4],a2[4],b0[4],b1[4];
    float acc[4][4];
#pragma unroll
    for (int i = 0; i < 4; i++) {
        int n = nb + i*256;
        a0[i]=W[n]; a1[i]=W[NT+n]; a2[i]=W[2*NT+n]; b0[i]=W[3*NT+n]; b1[i]=W[4*NT+n];
#pragma unroll
        for (int c = 0; c < 4; c++) acc[i][c] = 0.f;
    }
#pragma unroll 4
    for (int m = 0; m < MC; m++) {
        float c0=sm[m][0], c1=sm[m][1], c2=sm[m][2], c3=sm[m][3], c4=sm[m][4];
        float u0=sm[m][5], u1v=sm[m][6], u2v=sm[m][7], u3v=sm[m][8];
#pragma unroll
        for (int i = 0; i < 4; i++) {
            float dt = fmaf(a0[i],c0, fmaf(a1[i],c1, fmaf(a2[i],c2, fmaf(b0[i],c3, b1[i]*c4))));
            float E = ex2(dt);
            acc[i][0] = fmaf(E,u0, acc[i][0]);
            acc[i][1] = fmaf(E,u1v,acc[i][1]);
            acc[i][2] = fmaf(E,u2v,acc[i][2]);
            acc[i][3] = fmaf(E,u3v,acc[i][3]);
        }
    }
#pragma unroll
    for (int i = 0; i < 4; i++) {
        int n = nb + i*256;
#pragma unroll
        for (int c = 0; c < 4; c++) y1p[(c*KC + k)*NT + n] = acc[i][c];
    }
}

// ------------------------------- exact separable spatial filter (K2 * u2)
// One block per channel. Single 512x17-padded LDS volume, in-place passes:
// each pass's rows partition the volume, rows register-resident, taps in regs.
__global__ __launch_bounds__(256) void k_spatial(const float* __restrict__ W,
                                                 float* __restrict__ y2s) {
    __shared__ float SP[512 * 17];
    const int c = blockIdx.x;
    const int tid = threadIdx.x;
    const float* u2 = W + (9 + c) * NT;
    for (int s = tid; s < NT; s += 256)
        SP[(s >> 4) * 17 + (s & 15)] = u2[s];
    float g16[16];
#pragma unroll
    for (int d = 0; d < 16; d++) { float t = d * INVA; g16[d] = ex2(-0.5f*t*t); }
    __syncthreads();
    // z-pass: rows (x,y), contiguous z at stride 17
#pragma unroll
    for (int rr = 0; rr < 2; rr++) {
        int r = tid + rr * 256;
        float v[16], acc[16];
#pragma unroll
        for (int z = 0; z < 16; z++) { v[z] = SP[r*17 + z]; acc[z] = 0.f; }
#pragma unroll
        for (int zp = 0; zp < 16; zp++) {
#pragma unroll
            for (int z = 0; z < 16; z++) {
                int d = (z > zp) ? (z - zp) : (zp - z);
                acc[z] = fmaf(g16[d], v[zp], acc[z]);
            }
        }
#pragma unroll
        for (int z = 0; z < 16; z++) SP[r*17 + z] = acc[z];
    }
    __syncthreads();
    // y-pass: rows (x,z), stride 17 floats between y's
#pragma unroll
    for (int rr = 0; rr < 2; rr++) {
        int r = tid + rr * 256;
        int x = r >> 4, z = r & 15;
        int base = x * 272 + z;            // (x*16)*17 + z
        float v[16], acc[16];
#pragma unroll
        for (int y = 0; y < 16; y++) { v[y] = SP[base + y*17]; acc[y] = 0.f; }
#pragma unroll
        for (int yp = 0; yp < 16; yp++) {
#pragma unroll
            for (int y = 0; y < 16; y++) {
                int d = (y > yp) ? (y - yp) : (yp - y);
                acc[y] = fmaf(g16[d], v[yp], acc[y]);
            }
        }
#pragma unroll
        for (int y = 0; y < 16; y++) SP[base + y*17] = acc[y];
    }
    __syncthreads();
    // x-pass: rows (y,z), stride 272 floats; write result to global
    {
        float g32[32];
#pragma unroll
        for (int d = 0; d < 32; d++) { float t = d * INVA; g32[d] = ex2(-0.5f*t*t); }
        int base = (tid >> 4) * 17 + (tid & 15);   // y*17 + z
        float v[32], acc[32];
#pragma unroll
        for (int xp = 0; xp < 32; xp++) { v[xp] = SP[base + xp*272]; acc[xp] = 0.f; }
#pragma unroll
        for (int xp = 0; xp < 32; xp++) {
#pragma unroll
            for (int x = 0; x < 32; x++) {
                int d = (x > xp) ? (x - xp) : (xp - x);
                acc[x] = fmaf(g32[d], v[xp], acc[x]);
            }
        }
#pragma unroll
        for (int x = 0; x < 32; x++) y2s[c*NT + x*256 + tid] = acc[x];
    }
}

// ---------------------- reduce partials, combine, compat, softmax, next u
template<int KC>
__global__ __launch_bounds__(256) void k_update(float* __restrict__ W,
        const float* __restrict__ y1p, const float* __restrict__ y2s,
        const float* __restrict__ lu, const float* __restrict__ compat,
        float* __restrict__ out) {
    constexpr int KG = KC / 8;
    __shared__ float red[4][8][32];
    int nl = threadIdx.x & 31, kg = threadIdx.x >> 5;
    int n = blockIdx.x * 32 + nl;
    float p[4] = {0.f, 0.f, 0.f, 0.f};
    for (int kk = kg*KG; kk < kg*KG + KG; kk++)
#pragma unroll
        for (int c = 0; c < 4; c++) p[c] += y1p[(c*KC + kk)*NT + n];
#pragma unroll
    for (int c = 0; c < 4; c++) red[c][kg][nl] = p[c];
    __syncthreads();
    if (threadIdx.x < 32) {
        n = blockIdx.x * 32 + threadIdx.x;
        float f1 = W[14*NT+n], s2 = W[15*NT+n];
        float comb[4];
#pragma unroll
        for (int c = 0; c < 4; c++) {
            float sa = 0.f;
#pragma unroll
            for (int g = 0; g < 8; g++) sa += red[c][g][threadIdx.x];
            comb[c] = f1 * sa + s2 * y2s[c*NT + n];
        }
        float q[4];
#pragma unroll
        for (int o = 0; o < 4; o++) {
            float upd = 0.f;
#pragma unroll
            for (int c = 0; c < 4; c++) upd = fmaf(compat[o*4+c], comb[c], upd);
            q[o] = lu[o*NT+n] - upd;
        }
        float mx = fmaxf(fmaxf(q[0],q[1]), fmaxf(q[2],q[3]));
        float sum = 0.f;
#pragma unroll
        for (int c = 0; c < 4; c++) { q[c] = __expf(q[c]-mx); sum += q[c]; }
        float inv = 1.f / sum;
#pragma unroll
        for (int c = 0; c < 4; c++) {
            q[c] *= inv;
            out[c*NT+n]   = q[c];       // last iteration's write is the answer
            W[(5+c)*NT+n] = q[c]*f1;    // u1 next iter
            W[(9+c)*NT+n] = q[c]*s2;    // u2 next iter
        }
    }
}

// ---------------------------------------------------------------- driver
template<int KC>
static void run_all(const float* lu, const float* compat, float* out,
                    float* W, hipStream_t stream) {
    float* rs1p = W + 20*NT;     // aliases y1p (consumed before first k_pair)
    float* y1p  = W + 20*NT;
    float* y2s  = W + 16*NT;
    k_norm<KC><<<dim3(KC, 8), dim3(256), 0, stream>>>(W, rs1p);
    k_scale_init<KC><<<dim3(256), dim3(256), 0, stream>>>(W, rs1p, lu);
    for (int it = 0; it < 5; it++) {
        k_pair<KC><<<dim3(KC, 8), dim3(256), 0, stream>>>(W, y1p);
        k_spatial<<<dim3(4), dim3(256), 0, stream>>>(W, y2s);
        k_update<KC><<<dim3(256), dim3(256), 0, stream>>>(W, y1p, y2s, lu, compat, out);
    }
}

extern "C" void kernel_launch(void* const* d_in, const int* in_sizes, int n_in,
                              void* d_out, int out_size, void* d_ws, size_t ws_size,
                              hipStream_t stream) {
    const float* lu     = (const float*)d_in[0];
    const float* feat   = (const float*)d_in[1];
    const float* compat = (const float*)d_in[2];
    float* out = (float*)d_out;
    float* W   = (float*)d_ws;

    k_setup<<<dim3(NT/256), dim3(256), 0, stream>>>(feat, W);

    if (ws_size >= (size_t)(20 + 4*128) * NT * sizeof(float)) {
        run_all<128>(lu, compat, out, W, stream);   // 17.4 MB, grid 1024 blocks
    } else {
        run_all<64>(lu, compat, out, W, stream);    //  9.1 MB, grid 512 blocks
    }
}

// Round 3
// 147.248 us; speedup vs baseline: 2.5873x; 1.7901x over previous
//
#include <hip/hip_runtime.h>
#include <math.h>

// CRF mean-field, fully factorized — NO O(N^2) pass.
// Bilateral kernel: K1[n,m] = Ks(s_n-s_m) * e_g(n) e_g(m) * exp(g_n.g_m),
// g = img_features/5.  exp(g_n.g_m) is Taylor-expanded to degree 6 (exact to
// ~4e-5 for |t|<=0.72): rank-28 basis M_ab = e_g * g0^a g1^b / sqrt(a!b!).
// => bilateral filtering = 28x4 separable 3-D Gaussian convolutions + rank-28
// contract. Spatial kernel K2 = same separable conv (ALPHA=GAMMA=5), 4 more
// volumes in the same grid. N = 32*16*16 = 8192, C = 4, 5 iterations.

constexpr int   NT    = 8192;
constexpr float SQL2E = 1.2011224087864498f;     // sqrt(log2 e)
constexpr float LOG2E = 1.4426950408889634f;
constexpr float INVA  = 0.2f * SQL2E;            // spatial prescale: (1/5)*sqrt(log2 e)

// W rows (NT floats each):
//   0..27  : M[ab]            (Taylor basis, e_g folded in)
//   28..31 : (unused)
//   32..35 : u1[c] = q*scale1
//   36..39 : u2[c] = q*scale2
//   40     : scale1     41 : scale2
//   42..157: cv[idx] conv outputs (norm pass uses 42..69; iter pass 42..157;
//            rows 42+112..42+115 are the K2-filtered u2 channels)
constexpr int R_M = 0, R_U1 = 32, R_U2 = 36, R_S1 = 40, R_S2 = 41, R_CV = 42;

static __device__ __forceinline__ float ex2(float x) {
    return __builtin_amdgcn_exp2f(x);
}

__constant__ float INVSQF[7] = {1.f, 1.f, 0.70710678f, 0.40824829f,
                                0.20412415f, 0.09128709f, 0.03726780f};

// ---------------------------------------------------------------- setup
// Build M[28] basis rows and closed-form scale2 (separable spatial rowsum).
__global__ __launch_bounds__(256) void k_setup(const float* __restrict__ feat,
                                               float* __restrict__ W) {
    int n = blockIdx.x * 256 + threadIdx.x;
    float g0 = feat[n] * 0.2f, g1 = feat[NT + n] * 0.2f;   // natural domain
    float eg = ex2(-0.5f * LOG2E * (g0*g0 + g1*g1));
    float p0[7], p1[7];
    p0[0] = 1.f; p1[0] = 1.f;
#pragma unroll
    for (int i = 1; i < 7; i++) { p0[i] = p0[i-1]*g0; p1[i] = p1[i-1]*g1; }
    int ab = 0;
#pragma unroll
    for (int k = 0; k <= 6; k++)
#pragma unroll
        for (int a = k; a >= 0; a--) {
            int b = k - a;
            W[(R_M + ab)*NT + n] = eg * p0[a]*INVSQF[a] * p1[b]*INVSQF[b];
            ab++;
        }
    // spatial rowsum (exact separable product) -> scale2
    int x = n >> 8, y = (n >> 4) & 15, z = n & 15;
    float Sx = 0.f, Sy = 0.f, Sz = 0.f;
    for (int j = 0; j < 32; j++) { float d = (float)(x-j)*INVA; Sx += ex2(-0.5f*d*d); }
    for (int j = 0; j < 16; j++) { float d = (float)(y-j)*INVA; Sy += ex2(-0.5f*d*d); }
    for (int j = 0; j < 16; j++) { float d = (float)(z-j)*INVA; Sz += ex2(-0.5f*d*d); }
    W[R_S2*NT + n] = rsqrtf(Sx * Sy * Sz);
}

// ------------------------------------- separable 3-D Gaussian conv (1 vol/block)
// mode 0: P = M[ab], ab = blockIdx (norm pass, 28 blocks)
// mode 1: idx<112: P = M[idx>>2] * u1[idx&3];  idx>=112: P = u2[idx-112]
__global__ __launch_bounds__(256) void k_conv(const float* __restrict__ W,
                                              float* __restrict__ Wout, int mode) {
    __shared__ float SP[512 * 17];
    const int idx = blockIdx.x;
    const int tid = threadIdx.x;
    if (mode == 0) {
        const float* src = W + (R_M + idx) * NT;
        for (int s = tid; s < NT; s += 256)
            SP[(s >> 4)*17 + (s & 15)] = src[s];
    } else if (idx < 112) {
        const float* Mr = W + (R_M + (idx >> 2)) * NT;
        const float* ur = W + (R_U1 + (idx & 3)) * NT;
        for (int s = tid; s < NT; s += 256)
            SP[(s >> 4)*17 + (s & 15)] = Mr[s] * ur[s];
    } else {
        const float* ur = W + (R_U2 + (idx - 112)) * NT;
        for (int s = tid; s < NT; s += 256)
            SP[(s >> 4)*17 + (s & 15)] = ur[s];
    }
    float g32[32];
#pragma unroll
    for (int d = 0; d < 32; d++) { float t = d * INVA; g32[d] = ex2(-0.5f*t*t); }
    __syncthreads();
    // z-pass: rows (x,y) at stride 17
#pragma unroll
    for (int rr = 0; rr < 2; rr++) {
        int r = tid + rr * 256;
        float v[16], acc[16];
#pragma unroll
        for (int z = 0; z < 16; z++) { v[z] = SP[r*17 + z]; acc[z] = 0.f; }
#pragma unroll
        for (int zp = 0; zp < 16; zp++)
#pragma unroll
            for (int z = 0; z < 16; z++) {
                int d = (z > zp) ? (z - zp) : (zp - z);
                acc[z] = fmaf(g32[d], v[zp], acc[z]);
            }
#pragma unroll
        for (int z = 0; z < 16; z++) SP[r*17 + z] = acc[z];
    }
    __syncthreads();
    // y-pass: rows (x,z), stride 17 between y's
#pragma unroll
    for (int rr = 0; rr < 2; rr++) {
        int r = tid + rr * 256;
        int x = r >> 4, z = r & 15;
        int base = x * 272 + z;
        float v[16], acc[16];
#pragma unroll
        for (int y = 0; y < 16; y++) { v[y] = SP[base + y*17]; acc[y] = 0.f; }
#pragma unroll
        for (int yp = 0; yp < 16; yp++)
#pragma unroll
            for (int y = 0; y < 16; y++) {
                int d = (y > yp) ? (y - yp) : (yp - y);
                acc[y] = fmaf(g32[d], v[yp], acc[y]);
            }
#pragma unroll
        for (int y = 0; y < 16; y++) SP[base + y*17] = acc[y];
    }
    __syncthreads();
    // x-pass: rows (y,z), stride 272; write to global
    {
        int base = (tid >> 4) * 17 + (tid & 15);     // 17*y + z
        float v[32], acc[32];
#pragma unroll
        for (int xp = 0; xp < 32; xp++) { v[xp] = SP[base + xp*272]; acc[xp] = 0.f; }
#pragma unroll
        for (int xp = 0; xp < 32; xp++)
#pragma unroll
            for (int x = 0; x < 32; x++) {
                int d = (x > xp) ? (x - xp) : (xp - x);
                acc[x] = fmaf(g32[d], v[xp], acc[x]);
            }
        float* outp = Wout + (R_CV + idx) * NT;
#pragma unroll
        for (int x = 0; x < 32; x++) outp[x*256 + tid] = acc[x];
    }
}

// ---------------------------- init: rowsum1 contract, scale1, q0, u1, u2
__global__ __launch_bounds__(256) void k_init(float* __restrict__ W,
                                              const float* __restrict__ lu) {
    int n = blockIdx.x * 256 + threadIdx.x;
    float rs = 0.f;
#pragma unroll
    for (int ab = 0; ab < 28; ab++)
        rs = fmaf(W[(R_M+ab)*NT + n], W[(R_CV+ab)*NT + n], rs);
    float s1 = rsqrtf(rs);
    float s2 = W[R_S2*NT + n];
    W[R_S1*NT + n] = s1;
    float l0 = lu[n], l1 = lu[NT+n], l2 = lu[2*NT+n], l3 = lu[3*NT+n];
    float mx = fmaxf(fmaxf(l0,l1), fmaxf(l2,l3));
    float q0 = __expf(l0-mx), q1 = __expf(l1-mx), q2 = __expf(l2-mx), q3 = __expf(l3-mx);
    float inv = 1.f / (q0+q1+q2+q3);
    q0*=inv; q1*=inv; q2*=inv; q3*=inv;
    W[(R_U1+0)*NT+n]=q0*s1; W[(R_U1+1)*NT+n]=q1*s1; W[(R_U1+2)*NT+n]=q2*s1; W[(R_U1+3)*NT+n]=q3*s1;
    W[(R_U2+0)*NT+n]=q0*s2; W[(R_U2+1)*NT+n]=q1*s2; W[(R_U2+2)*NT+n]=q2*s2; W[(R_U2+3)*NT+n]=q3*s2;
}

// -------------------- fuse: rank-28 contract, combine, compat, softmax, next u
__global__ __launch_bounds__(256) void k_fuse(float* __restrict__ W,
        const float* __restrict__ lu, const float* __restrict__ compat,
        float* __restrict__ out) {
    int n = blockIdx.x * 256 + threadIdx.x;
    float s1 = W[R_S1*NT + n], s2 = W[R_S2*NT + n];
    float q1[4] = {0.f, 0.f, 0.f, 0.f};
#pragma unroll
    for (int ab = 0; ab < 28; ab++) {
        float m = W[(R_M+ab)*NT + n];
#pragma unroll
        for (int c = 0; c < 4; c++)
            q1[c] = fmaf(m, W[(R_CV + ab*4 + c)*NT + n], q1[c]);
    }
    float comb[4];
#pragma unroll
    for (int c = 0; c < 4; c++)
        comb[c] = s1 * q1[c] + s2 * W[(R_CV + 112 + c)*NT + n];
    float q[4];
#pragma unroll
    for (int o = 0; o < 4; o++) {
        float upd = 0.f;
#pragma unroll
        for (int c = 0; c < 4; c++) upd = fmaf(compat[o*4+c], comb[c], upd);
        q[o] = lu[o*NT+n] - upd;
    }
    float mx = fmaxf(fmaxf(q[0],q[1]), fmaxf(q[2],q[3]));
    float sum = 0.f;
#pragma unroll
    for (int c = 0; c < 4; c++) { q[c] = __expf(q[c]-mx); sum += q[c]; }
    float inv = 1.f / sum;
#pragma unroll
    for (int c = 0; c < 4; c++) {
        q[c] *= inv;
        out[c*NT+n]        = q[c];      // last iteration's write is the answer
        W[(R_U1+c)*NT+n]   = q[c]*s1;
        W[(R_U2+c)*NT+n]   = q[c]*s2;
    }
}

// ---------------------------------------------------------------- driver
extern "C" void kernel_launch(void* const* d_in, const int* in_sizes, int n_in,
                              void* d_out, int out_size, void* d_ws, size_t ws_size,
                              hipStream_t stream) {
    const float* lu     = (const float*)d_in[0];
    const float* feat   = (const float*)d_in[1];
    const float* compat = (const float*)d_in[2];
    float* out = (float*)d_out;
    float* W   = (float*)d_ws;     // needs 158*NT*4 = 5.2 MB

    k_setup<<<dim3(32), dim3(256), 0, stream>>>(feat, W);
    k_conv <<<dim3(28), dim3(256), 0, stream>>>(W, W, 0);     // norm pass
    k_init <<<dim3(32), dim3(256), 0, stream>>>(W, lu);
    for (int it = 0; it < 5; it++) {
        k_conv<<<dim3(116), dim3(256), 0, stream>>>(W, W, 1);
        k_fuse<<<dim3(32),  dim3(256), 0, stream>>>(W, lu, compat, out);
    }
}